// Round 10
// baseline (203.316 us; speedup 1.0000x reference)
//
#include <hip/hip_runtime.h>

// ZeroPad2d: in [32,2048,2048] f32 -> out [32,2050,2050] f32, pad=1.
// R10: BOTH-streams-aligned float4 via LDS realignment (m13-copy-identical
// global instruction mix; the only untested cell of the alignment matrix).
//   - one 256-thread block per OUTPUT row, grid (2050, 32); p = y&1
//   - thread t: 2 aligned f32x4 loads (row chunks t, t+256)
//   - LDS logical L[j] = in[j-1], L[0] = L[2049] = 0 (pad zeros live in LDS;
//     no cndmask, no patch loads). Physical index phys(j) = j + (j>>2):
//     per-lane stride 5 dwords, coprime with 32 banks -> 2-way (free, m136);
//     naive stride-4 would be 8-way (2.94x).
//   - one barrier; thread t reads L[2p+4k+r] (k = t, t+256) and does 2
//     ALIGNED f32x4 stores at out + s + 2p + 4k; lane 0 stores the row's
//     leftover 2 dwords as an aligned f32x2 at s + (p ? 0 : 2048).
//   - pad rows (y=0,2049): 8 dword zero-stores (as R8).
// Every output element is written on every call (harness does not re-poison).

#define H 2048
#define W 2048
#define HPAD 2050
#define WPAD 2050
#define LDSN 2562   // phys(2049) = 2049 + 512 = 2561

typedef float f32x4 __attribute__((ext_vector_type(4)));
typedef float f32x2 __attribute__((ext_vector_type(2)));

__device__ __forceinline__ unsigned physi(unsigned j) { return j + (j >> 2); }

__global__ __launch_bounds__(256) void zeropad_lds(const float* __restrict__ in,
                                                   float* __restrict__ out) {
    __shared__ float L[LDSN];
    const unsigned y = blockIdx.x;     // 0..2049 (padded row)
    const unsigned c = blockIdx.y;     // 0..31
    const unsigned t = threadIdx.x;    // 0..255
    float* orow = out + ((size_t)c * HPAD + y) * WPAD;

    if (y >= 1u && y <= (unsigned)H) {
        const float* srow = in + ((size_t)c * H + (y - 1u)) * W;

        // aligned 16B loads: chunks t and t+256
        f32x4 a = *(const f32x4*)(srow + 4u * t);
        f32x4 b = *(const f32x4*)(srow + 4u * t + 1024u);

        // stage: L[j] = in[j-1]  (j = 4t+r+1, 4t+r+1025), swizzled stride-5
        #pragma unroll
        for (int r = 0; r < 4; ++r) {
            const unsigned j0 = 4u * t + (unsigned)r + 1u;
            const unsigned j1 = j0 + 1024u;
            L[physi(j0)] = a[r];
            L[physi(j1)] = b[r];
        }
        if (t == 0u) {                  // pad-zero slots
            L[physi(0u)]    = 0.f;
            L[physi(2049u)] = 0.f;
        }
        __syncthreads();

        const unsigned p = y & 1u;      // h = y-1; h even -> p=1 (s%4==2)
        f32x4 v0, v1;
        #pragma unroll
        for (int r = 0; r < 4; ++r) {
            const unsigned j0 = 2u * p + 4u * t + (unsigned)r;
            const unsigned j1 = j0 + 1024u;
            v0[r] = L[physi(j0)];
            v1[r] = L[physi(j1)];
        }
        // aligned 16B stores: out row positions [2p .. 2p+2047]
        *(f32x4*)(orow + 2u * p + 4u * t)          = v0;
        *(f32x4*)(orow + 2u * p + 4u * t + 1024u)  = v1;

        if (t == 0u) {                  // leftover 2 dwords, aligned 8B store
            const unsigned m = p ? 0u : 2048u;
            f32x2 w;
            w[0] = L[physi(m)];
            w[1] = L[physi(m + 1u)];
            *(f32x2*)(orow + m) = w;
        }
    } else {
        // top/bottom pad row: 2050 zeros (R8 pattern)
        #pragma unroll
        for (int j = 0; j < 8; ++j)
            orow[t + 256u * j] = 0.f;
        if (t < 2u) orow[2048u + t] = 0.f;
    }
}

extern "C" void kernel_launch(void* const* d_in, const int* in_sizes, int n_in,
                              void* d_out, int out_size, void* d_ws, size_t ws_size,
                              hipStream_t stream) {
    const float* in = (const float*)d_in[0];
    float* out = (float*)d_out;
    dim3 grid(HPAD, 32);               // 2050 rows x 32 channels
    zeropad_lds<<<grid, 256, 0, stream>>>(in, out);
}